// Round 2
// baseline (256.833 us; speedup 1.0000x reference)
//
#include <hip/hip_runtime.h>
#include <hip/hip_bf16.h>

// ParallelGNNBlock: out = concat(0.99 * GCN_sparse(x,W1,b1), 0.01 * GCN_2hop(x,W2,b2))
// N=8192 nodes, D_IN=512, D_OUT=128, E=131072 edges.
//
// Pipeline (8 dispatches):
//  1. k_zero    : zero cnt/fill/AT bitset
//  2. k_hist    : in-degree histogram over dst
//  3. k_scan    : exclusive prefix sum -> row_ptr; dinv1 = rsqrt(deg+1)
//  4. k_scatter : CSR src lists by dst + AT bitset (AT[d] bit s <=> edge s->d)
//  5. k_a2t     : A2T[i] = OR_{k in bits(AT[i])} AT[k]; dinv2 = rsqrt(popcount+1)
//  6. k_gemm    : g1 = dinv1 .* (x@W1), g2 = dinv2 .* (x@W2)   (fused scale epilogue)
//  7. k_spmm1   : out[:, :128] = 0.99*(dinv1[i]*(sum_e g1[src] + g1[i]) + b1)
//  8. k_spmm2   : out[:,128:] = 0.01*(dinv2[i]*(sum_bits g2[j] + g2[i]) + b2)

#define NN   8192
#define NE   131072
#define DIN  512
#define DO   128

// ---------------- workspace layout (bytes), ~25.6 MB ----------------
static constexpr size_t OFF_G1   = 0;                      // 8192*128*4 = 4 MB
static constexpr size_t OFF_G2   = OFF_G1   + 4194304;     // 4 MB
static constexpr size_t OFF_AT   = OFF_G2   + 4194304;     // 8 MB (u64[8192][128])
static constexpr size_t OFF_A2T  = OFF_AT   + 8388608;     // 8 MB
static constexpr size_t OFF_CNT  = OFF_A2T  + 8388608;     // 32 KB
static constexpr size_t OFF_FILL = OFF_CNT  + 32768;       // 32 KB
static constexpr size_t OFF_RP   = OFF_FILL + 32768;       // 8193*4 -> pad 33024
static constexpr size_t OFF_CSR  = OFF_RP   + 33024;       // 512 KB
static constexpr size_t OFF_DI1  = OFF_CSR  + 524288;      // 32 KB
static constexpr size_t OFF_DI2  = OFF_DI1  + 32768;       // 32 KB

// ---------------- kernels ----------------

__global__ void k_zero(unsigned long long* __restrict__ AT,
                       unsigned* __restrict__ cnt, unsigned* __restrict__ fill) {
  size_t tid = (size_t)blockIdx.x * blockDim.x + threadIdx.x;
  size_t stride = (size_t)gridDim.x * blockDim.x;
  for (size_t i = tid; i < (size_t)NN * 128; i += stride) AT[i] = 0ull;
  if (tid < NN) { cnt[tid] = 0u; fill[tid] = 0u; }
}

__global__ void k_hist(const int* __restrict__ ei, unsigned* __restrict__ cnt) {
  int e = blockIdx.x * blockDim.x + threadIdx.x;
  if (e >= NE) return;
  atomicAdd(&cnt[ei[NE + e]], 1u);
}

__global__ __launch_bounds__(1024) void k_scan(const unsigned* __restrict__ cnt,
                                               unsigned* __restrict__ row_ptr,
                                               float* __restrict__ dinv1) {
  __shared__ unsigned sums[1024];
  int t = threadIdx.x;
  unsigned v[8];
  unsigned s = 0;
  #pragma unroll
  for (int i = 0; i < 8; i++) { v[i] = cnt[t * 8 + i]; s += v[i]; }
  sums[t] = s;
  __syncthreads();
  for (int off = 1; off < 1024; off *= 2) {
    unsigned add = (t >= off) ? sums[t - off] : 0u;
    __syncthreads();
    sums[t] += add;
    __syncthreads();
  }
  unsigned base = (t == 0) ? 0u : sums[t - 1];
  #pragma unroll
  for (int i = 0; i < 8; i++) {
    row_ptr[t * 8 + i] = base;
    base += v[i];
    dinv1[t * 8 + i] = rsqrtf((float)v[i] + 1.0f);
  }
  if (t == 1023) row_ptr[NN] = base;   // = NE
}

__global__ void k_scatter(const int* __restrict__ ei, const unsigned* __restrict__ row_ptr,
                          unsigned* __restrict__ fill, unsigned* __restrict__ csr_src,
                          unsigned long long* __restrict__ AT) {
  int e = blockIdx.x * blockDim.x + threadIdx.x;
  if (e >= NE) return;
  int s = ei[e];
  int d = ei[NE + e];
  unsigned pos = atomicAdd(&fill[d], 1u);
  csr_src[row_ptr[d] + pos] = (unsigned)s;
  atomicOr(&AT[(size_t)d * 128 + (s >> 6)], 1ull << (s & 63));
}

// A2T[i] = union of AT[k] over k in bits(AT[i]); dinv2[i] = rsqrt(popcount+1)
// Two-phase: expand bits -> shared ushort list (prefix scan), then unrolled gather.
__global__ __launch_bounds__(128) void k_a2t(const unsigned long long* __restrict__ AT,
                                             unsigned long long* __restrict__ A2T,
                                             float* __restrict__ dinv2) {
  const int i = blockIdx.x, t = threadIdx.x;
  __shared__ unsigned pc[128];
  __shared__ unsigned short list[8192];
  unsigned long long w0 = AT[(size_t)i * 128 + t];
  pc[t] = (unsigned)__popcll(w0);
  __syncthreads();
  for (int off = 1; off < 128; off <<= 1) {
    unsigned add = (t >= off) ? pc[t - off] : 0u;
    __syncthreads();
    pc[t] += add;
    __syncthreads();
  }
  unsigned base = (t == 0) ? 0u : pc[t - 1];
  const unsigned total = pc[127];
  unsigned long long m = w0;
  while (m) {
    int b = __ffsll(m) - 1;
    m &= m - 1;
    list[base++] = (unsigned short)(t * 64 + b);
  }
  __syncthreads();
  unsigned long long acc = 0ull;
  #pragma unroll 4
  for (unsigned k = 0; k < total; k++)
    acc |= AT[(size_t)list[k] * 128 + t];          // coalesced 1 KB row per k
  A2T[(size_t)i * 128 + t] = acc;
  __syncthreads();                                  // pc reuse
  pc[t] = (unsigned)__popcll(acc);
  __syncthreads();
  for (int s = 64; s > 0; s >>= 1) {
    if (t < s) pc[t] += pc[t + s];
    __syncthreads();
  }
  if (t == 0) dinv2[i] = rsqrtf((float)pc[0] + 1.0f);
}

// g1 = dinv1 .* (x@W1), g2 = dinv2 .* (x@W2); 64x64 tiles, 256 thr, 4x4 micro-tile.
__global__ __launch_bounds__(256) void k_gemm(const float* __restrict__ x,
                                              const float* __restrict__ W1,
                                              const float* __restrict__ W2,
                                              const float* __restrict__ dinv1,
                                              const float* __restrict__ dinv2,
                                              float* __restrict__ g1,
                                              float* __restrict__ g2) {
  const int bm = blockIdx.x;                 // 0..127
  const int bn = blockIdx.y;                 // 0..3
  const float* __restrict__ W  = (bn < 2) ? W1 : W2;
  const float* __restrict__ dv = (bn < 2) ? dinv1 : dinv2;
  float* __restrict__ dst      = (bn < 2) ? g1 : g2;
  const int cb = (bn & 1) * 64;              // col offset inside the 128-wide W
  __shared__ float As[16][68];               // [k][m], pad 68 keeps float4 rows 16B-aligned
  __shared__ float Bs[16][64];               // [k][n]
  const int t = threadIdx.x;
  const int tx = t & 15, ty = t >> 4;
  const int row0 = bm * 64;
  float acc[4][4] = {};
  for (int k0 = 0; k0 < DIN; k0 += 16) {
    {
      int ar = t >> 2, ak = (t & 3) * 4;
      const float4 a4 = *(const float4*)&x[(size_t)(row0 + ar) * DIN + k0 + ak];
      As[ak + 0][ar] = a4.x; As[ak + 1][ar] = a4.y;
      As[ak + 2][ar] = a4.z; As[ak + 3][ar] = a4.w;
    }
    {
      int col = t & 63, kk = t >> 6;
      #pragma unroll
      for (int u = 0; u < 4; u++, kk += 4)
        Bs[kk][col] = W[(size_t)(k0 + kk) * DO + cb + col];
    }
    __syncthreads();
    #pragma unroll
    for (int k = 0; k < 16; k++) {
      float4 a4 = *(const float4*)&As[k][ty * 4];
      float4 b4 = *(const float4*)&Bs[k][tx * 4];
      float a[4] = {a4.x, a4.y, a4.z, a4.w};
      float b[4] = {b4.x, b4.y, b4.z, b4.w};
      #pragma unroll
      for (int i = 0; i < 4; i++)
        #pragma unroll
        for (int j = 0; j < 4; j++)
          acc[i][j] += a[i] * b[j];
    }
    __syncthreads();
  }
  #pragma unroll
  for (int i = 0; i < 4; i++) {
    const int r = row0 + ty * 4 + i;
    const float s = dv[r];
    float4 v = {acc[i][0] * s, acc[i][1] * s, acc[i][2] * s, acc[i][3] * s};
    *(float4*)&dst[(size_t)r * DO + cb + tx * 4] = v;
  }
}

__global__ __launch_bounds__(128) void k_spmm1(const float* __restrict__ g1,
                                               const unsigned* __restrict__ row_ptr,
                                               const unsigned* __restrict__ csr_src,
                                               const float* __restrict__ dinv1,
                                               const float* __restrict__ b1,
                                               float* __restrict__ out) {
  const int i = blockIdx.x, d = threadIdx.x;
  float acc = g1[(size_t)i * DO + d];                 // self-loop term (dinv^2 * h)
  const unsigned lo = row_ptr[i], hi = row_ptr[i + 1];
  #pragma unroll 4
  for (unsigned e = lo; e < hi; e++)
    acc += g1[(size_t)csr_src[e] * DO + d];
  out[(size_t)i * 256 + d] = 0.99f * (dinv1[i] * acc + b1[d]);
}

__global__ __launch_bounds__(128) void k_spmm2(const float* __restrict__ g2,
                                               const unsigned long long* __restrict__ A2T,
                                               const float* __restrict__ dinv2,
                                               const float* __restrict__ b2,
                                               float* __restrict__ out) {
  const int i = blockIdx.x, t = threadIdx.x;
  __shared__ unsigned pc[128];
  __shared__ unsigned short list[8192];
  unsigned long long w0 = A2T[(size_t)i * 128 + t];
  pc[t] = (unsigned)__popcll(w0);
  __syncthreads();
  for (int off = 1; off < 128; off <<= 1) {
    unsigned add = (t >= off) ? pc[t - off] : 0u;
    __syncthreads();
    pc[t] += add;
    __syncthreads();
  }
  unsigned base = (t == 0) ? 0u : pc[t - 1];
  const unsigned total = pc[127];
  unsigned long long m = w0;
  while (m) {
    int b = __ffsll(m) - 1;
    m &= m - 1;
    list[base++] = (unsigned short)(t * 64 + b);
  }
  __syncthreads();
  float acc = g2[(size_t)i * DO + t];                 // appended self-loop (always +1)
  #pragma unroll 4
  for (unsigned k = 0; k < total; k++)
    acc += g2[(size_t)list[k] * DO + t];              // coalesced 512 B row per k
  out[(size_t)i * 256 + 128 + t] = 0.01f * (dinv2[i] * acc + b2[t]);
}

// ---------------- launch ----------------

extern "C" void kernel_launch(void* const* d_in, const int* in_sizes, int n_in,
                              void* d_out, int out_size, void* d_ws, size_t ws_size,
                              hipStream_t stream) {
  const float* x  = (const float*)d_in[0];
  const int*   ei = (const int*)d_in[1];     // int32 per harness dtype rules
  const float* W1 = (const float*)d_in[2];
  const float* b1 = (const float*)d_in[3];
  const float* W2 = (const float*)d_in[4];
  const float* b2 = (const float*)d_in[5];
  float* out = (float*)d_out;
  char* ws = (char*)d_ws;

  float* g1                  = (float*)(ws + OFF_G1);
  float* g2                  = (float*)(ws + OFF_G2);
  unsigned long long* AT     = (unsigned long long*)(ws + OFF_AT);
  unsigned long long* A2T    = (unsigned long long*)(ws + OFF_A2T);
  unsigned* cnt              = (unsigned*)(ws + OFF_CNT);
  unsigned* fill             = (unsigned*)(ws + OFF_FILL);
  unsigned* row_ptr          = (unsigned*)(ws + OFF_RP);
  unsigned* csr_src          = (unsigned*)(ws + OFF_CSR);
  float* dinv1               = (float*)(ws + OFF_DI1);
  float* dinv2               = (float*)(ws + OFF_DI2);

  k_zero<<<1024, 256, 0, stream>>>(AT, cnt, fill);
  k_hist<<<NE / 256, 256, 0, stream>>>(ei, cnt);
  k_scan<<<1, 1024, 0, stream>>>(cnt, row_ptr, dinv1);
  k_scatter<<<NE / 256, 256, 0, stream>>>(ei, row_ptr, fill, csr_src, AT);
  k_a2t<<<NN, 128, 0, stream>>>(AT, A2T, dinv2);
  dim3 gg(NN / 64, 4);
  k_gemm<<<gg, 256, 0, stream>>>(x, W1, W2, dinv1, dinv2, g1, g2);
  k_spmm1<<<NN, 128, 0, stream>>>(g1, row_ptr, csr_src, dinv1, b1, out);
  k_spmm2<<<NN, 128, 0, stream>>>(g2, A2T, dinv2, b2, out);
}

// Round 4
// 209.558 us; speedup vs baseline: 1.2256x; 1.2256x over previous
//
#include <hip/hip_runtime.h>
#include <hip/hip_bf16.h>

// ParallelGNNBlock: out = concat(0.99 * GCN_sparse(x,W1,b1), 0.01 * GCN_2hop(x,W2,b2))
// N=8192 nodes, D_IN=512, D_OUT=128, E=131072 edges.
//
// Pipeline (8 dispatches):
//  1. k_zero    : zero cnt/fill/AT bitset
//  2. k_hist    : in-degree histogram over dst
//  3. k_scan    : exclusive prefix sum -> row_ptr; dinv1 = rsqrt(deg+1)
//  4. k_scatter : CSR src lists by dst + AT bitset (AT[d] bit s <=> edge s->d)
//  5. k_a2t     : A2T[i] = OR_{k in bits(AT[i])} AT[k]; dinv2 = rsqrt(popcount+1)
//  6. k_gemm    : g1 = dinv1 .* (x@W1) [f32], g2b = dinv2 .* (x@W2) [bf16]
//  7. k_spmm1   : out[:, :128] = 0.99*(dinv1[i]*(sum_e g1[src] + g1[i]) + b1)
//  8. k_spmm2   : out[:,128:] = 0.01*(dinv2[i]*(sum_bits g2[j] + g2[i]) + b2)

#define NN   8192
#define NE   131072
#define DIN  512
#define DO   128

using u64 = unsigned long long;

// ---------------- workspace layout (bytes), ~22.7 MB ----------------
static constexpr size_t OFF_G1   = 0;                      // 8192*128*4 = 4 MB (f32)
static constexpr size_t OFF_G2B  = OFF_G1   + 4194304;     // 8192*128*2 = 2 MB (bf16)
static constexpr size_t OFF_AT   = OFF_G2B  + 2097152;     // 8 MB (u64[8192][128])
static constexpr size_t OFF_A2T  = OFF_AT   + 8388608;     // 8 MB
static constexpr size_t OFF_CNT  = OFF_A2T  + 8388608;     // 32 KB
static constexpr size_t OFF_FILL = OFF_CNT  + 32768;       // 32 KB
static constexpr size_t OFF_RP   = OFF_FILL + 32768;       // 8193*4 -> pad 33024
static constexpr size_t OFF_CSR  = OFF_RP   + 33024;       // 512 KB
static constexpr size_t OFF_DI1  = OFF_CSR  + 524288;      // 32 KB
static constexpr size_t OFF_DI2  = OFF_DI1  + 32768;       // 32 KB

__device__ __forceinline__ unsigned short f2bf(float f) {
  unsigned u = __float_as_uint(f);
  return (unsigned short)((u + 0x7fffu + ((u >> 16) & 1u)) >> 16);   // RNE
}

// ---------------- kernels ----------------

__global__ void k_zero(u64* __restrict__ AT,
                       unsigned* __restrict__ cnt, unsigned* __restrict__ fill) {
  size_t tid = (size_t)blockIdx.x * blockDim.x + threadIdx.x;
  size_t stride = (size_t)gridDim.x * blockDim.x;
  for (size_t i = tid; i < (size_t)NN * 128; i += stride) AT[i] = 0ull;
  if (tid < NN) { cnt[tid] = 0u; fill[tid] = 0u; }
}

__global__ void k_hist(const int* __restrict__ ei, unsigned* __restrict__ cnt) {
  int e = blockIdx.x * blockDim.x + threadIdx.x;
  if (e >= NE) return;
  atomicAdd(&cnt[ei[NE + e]], 1u);
}

__global__ __launch_bounds__(1024) void k_scan(const unsigned* __restrict__ cnt,
                                               unsigned* __restrict__ row_ptr,
                                               float* __restrict__ dinv1) {
  __shared__ unsigned sums[1024];
  int t = threadIdx.x;
  unsigned v[8];
  unsigned s = 0;
  #pragma unroll
  for (int i = 0; i < 8; i++) { v[i] = cnt[t * 8 + i]; s += v[i]; }
  sums[t] = s;
  __syncthreads();
  for (int off = 1; off < 1024; off *= 2) {
    unsigned add = (t >= off) ? sums[t - off] : 0u;
    __syncthreads();
    sums[t] += add;
    __syncthreads();
  }
  unsigned base = (t == 0) ? 0u : sums[t - 1];
  #pragma unroll
  for (int i = 0; i < 8; i++) {
    row_ptr[t * 8 + i] = base;
    base += v[i];
    dinv1[t * 8 + i] = rsqrtf((float)v[i] + 1.0f);
  }
  if (t == 1023) row_ptr[NN] = base;   // = NE
}

__global__ void k_scatter(const int* __restrict__ ei, const unsigned* __restrict__ row_ptr,
                          unsigned* __restrict__ fill, unsigned* __restrict__ csr_src,
                          u64* __restrict__ AT) {
  int e = blockIdx.x * blockDim.x + threadIdx.x;
  if (e >= NE) return;
  int s = ei[e];
  int d = ei[NE + e];
  unsigned pos = atomicAdd(&fill[d], 1u);
  csr_src[row_ptr[d] + pos] = (unsigned)s;
  atomicOr(&AT[(size_t)d * 128 + (s >> 6)], 1ull << (s & 63));
}

// A2T[i] = union of AT[k] over k in bits(AT[i]); dinv2[i] = rsqrt(popcount+1)
// 512 threads: list build on t<128, 4-way k-split union, LDS OR-reduce.
__global__ __launch_bounds__(512) void k_a2t(const u64* __restrict__ AT,
                                             u64* __restrict__ A2T,
                                             float* __restrict__ dinv2) {
  const int i = blockIdx.x, t = threadIdx.x;
  __shared__ unsigned pc[128];
  __shared__ unsigned short list[512];     // 1-hop in-degree << 512
  __shared__ u64 redB[4][128];
  u64 w0 = 0ull;
  if (t < 128) {
    w0 = AT[(size_t)i * 128 + t];
    pc[t] = (unsigned)__popcll(w0);
  }
  __syncthreads();
  for (int off = 1; off < 128; off <<= 1) {
    unsigned add = (t >= off && t < 128) ? pc[t - off] : 0u;
    __syncthreads();
    if (t < 128) pc[t] += add;
    __syncthreads();
  }
  if (t < 128) {
    unsigned base = (t == 0) ? 0u : pc[t - 1];
    u64 m = w0;
    while (m) {
      int b = __ffsll(m) - 1;
      m &= m - 1;
      list[base++] = (unsigned short)(t * 64 + b);
    }
  }
  __syncthreads();
  const unsigned total = pc[127];
  const int q = t >> 7, c = t & 127;       // q in {0..3}
  u64 acc = 0ull;
  #pragma unroll 4
  for (unsigned k = q; k < total; k += 4)
    acc |= AT[(size_t)list[k] * 128 + c];  // coalesced 1 KB row per k
  redB[q][c] = acc;
  __syncthreads();
  if (t < 128) {
    u64 u = redB[0][t] | redB[1][t] | redB[2][t] | redB[3][t];
    A2T[(size_t)i * 128 + t] = u;
    pc[t] = (unsigned)__popcll(u);
  }
  __syncthreads();
  for (int s = 64; s > 0; s >>= 1) {
    if (t < s) pc[t] += pc[t + s];
    __syncthreads();
  }
  if (t == 0) dinv2[i] = rsqrtf((float)pc[0] + 1.0f);
}

// g1 = dinv1 .* (x@W1) f32; g2b = dinv2 .* (x@W2) bf16.
// 64x64 tiles, 256 threads, 4x4 micro-tile.
__global__ __launch_bounds__(256) void k_gemm(const float* __restrict__ x,
                                              const float* __restrict__ W1,
                                              const float* __restrict__ W2,
                                              const float* __restrict__ dinv1,
                                              const float* __restrict__ dinv2,
                                              float* __restrict__ g1,
                                              unsigned short* __restrict__ g2b) {
  const int bm = blockIdx.x;                 // 0..127
  const int bn = blockIdx.y;                 // 0..3
  const float* __restrict__ W  = (bn < 2) ? W1 : W2;
  const float* __restrict__ dv = (bn < 2) ? dinv1 : dinv2;
  const int cb = (bn & 1) * 64;              // col offset inside the 128-wide W
  __shared__ float As[16][68];               // [k][m], pad 68 keeps float4 rows 16B-aligned
  __shared__ float Bs[16][64];               // [k][n]
  const int t = threadIdx.x;
  const int tx = t & 15, ty = t >> 4;
  const int row0 = bm * 64;
  float acc[4][4] = {};
  for (int k0 = 0; k0 < DIN; k0 += 16) {
    {
      int ar = t >> 2, ak = (t & 3) * 4;
      const float4 a4 = *(const float4*)&x[(size_t)(row0 + ar) * DIN + k0 + ak];
      As[ak + 0][ar] = a4.x; As[ak + 1][ar] = a4.y;
      As[ak + 2][ar] = a4.z; As[ak + 3][ar] = a4.w;
    }
    {
      int col = t & 63, kk = t >> 6;
      #pragma unroll
      for (int u = 0; u < 4; u++, kk += 4)
        Bs[kk][col] = W[(size_t)(k0 + kk) * DO + cb + col];
    }
    __syncthreads();
    #pragma unroll
    for (int k = 0; k < 16; k++) {
      float4 a4 = *(const float4*)&As[k][ty * 4];
      float4 b4 = *(const float4*)&Bs[k][tx * 4];
      float a[4] = {a4.x, a4.y, a4.z, a4.w};
      float b[4] = {b4.x, b4.y, b4.z, b4.w};
      #pragma unroll
      for (int i = 0; i < 4; i++)
        #pragma unroll
        for (int j = 0; j < 4; j++)
          acc[i][j] += a[i] * b[j];
    }
    __syncthreads();
  }
  if (bn < 2) {
    #pragma unroll
    for (int i = 0; i < 4; i++) {
      const int r = row0 + ty * 4 + i;
      const float s = dv[r];
      float4 v = {acc[i][0] * s, acc[i][1] * s, acc[i][2] * s, acc[i][3] * s};
      *(float4*)&g1[(size_t)r * DO + cb + tx * 4] = v;
    }
  } else {
    #pragma unroll
    for (int i = 0; i < 4; i++) {
      const int r = row0 + ty * 4 + i;
      const float s = dv[r];
      ushort4 v = {f2bf(acc[i][0] * s), f2bf(acc[i][1] * s),
                   f2bf(acc[i][2] * s), f2bf(acc[i][3] * s)};
      *(ushort4*)&g2b[(size_t)r * DO + cb + tx * 4] = v;
    }
  }
}

// out[:, :128]; 256 threads: 4-way edge split, float2 per thread, LDS reduce.
__global__ __launch_bounds__(256) void k_spmm1(const float* __restrict__ g1,
                                               const unsigned* __restrict__ row_ptr,
                                               const unsigned* __restrict__ csr_src,
                                               const float* __restrict__ dinv1,
                                               const float* __restrict__ b1,
                                               float* __restrict__ out) {
  const int i = blockIdx.x, t = threadIdx.x;
  __shared__ float redA[4][128];
  const int q = t >> 6, c = t & 63;          // cols 2c, 2c+1
  const unsigned lo = row_ptr[i], hi = row_ptr[i + 1];
  float a0 = 0.f, a1 = 0.f;
  #pragma unroll 4
  for (unsigned e = lo + q; e < hi; e += 4) {
    unsigned j = csr_src[e];
    float2 v = *(const float2*)&g1[(size_t)j * DO + 2 * c];
    a0 += v.x; a1 += v.y;
  }
  redA[q][2 * c] = a0;
  redA[q][2 * c + 1] = a1;
  __syncthreads();
  if (t < 128) {
    float s = redA[0][t] + redA[1][t] + redA[2][t] + redA[3][t]
            + g1[(size_t)i * DO + t];        // self-loop term (dinv^2 * h)
    out[(size_t)i * 256 + t] = 0.99f * (dinv1[i] * s + b1[t]);
  }
}

// out[:,128:]; 256 threads: list build (t<128), 4-way k-split over bf16 rows.
__global__ __launch_bounds__(256) void k_spmm2(const unsigned short* __restrict__ g2b,
                                               const u64* __restrict__ A2T,
                                               const float* __restrict__ dinv2,
                                               const float* __restrict__ b2,
                                               float* __restrict__ out) {
  const int i = blockIdx.x, t = threadIdx.x;
  __shared__ unsigned pc[128];
  __shared__ unsigned short list[8192];
  __shared__ float redA[4][128];
  u64 w0 = 0ull;
  if (t < 128) {
    w0 = A2T[(size_t)i * 128 + t];
    pc[t] = (unsigned)__popcll(w0);
  }
  __syncthreads();
  for (int off = 1; off < 128; off <<= 1) {
    unsigned add = (t >= off && t < 128) ? pc[t - off] : 0u;
    __syncthreads();
    if (t < 128) pc[t] += add;
    __syncthreads();
  }
  if (t < 128) {
    unsigned base = (t == 0) ? 0u : pc[t - 1];
    u64 m = w0;
    while (m) {
      int b = __ffsll(m) - 1;
      m &= m - 1;
      list[base++] = (unsigned short)(t * 64 + b);
    }
  }
  __syncthreads();
  const unsigned total = pc[127];
  const int q = t >> 6, c = t & 63;          // cols 2c, 2c+1 (uint = 2 bf16)
  float a0 = 0.f, a1 = 0.f;
  #pragma unroll 4
  for (unsigned k = q; k < total; k += 4) {
    unsigned j = list[k];
    unsigned u = *(const unsigned*)&g2b[(size_t)j * DO + 2 * c];   // one 256B row/wave
    a0 += __uint_as_float(u << 16);
    a1 += __uint_as_float(u & 0xffff0000u);
  }
  redA[q][2 * c] = a0;
  redA[q][2 * c + 1] = a1;
  __syncthreads();
  if (t < 128) {
    unsigned us = g2b[(size_t)i * DO + t];
    float self = __uint_as_float((unsigned)us << 16);
    float s = redA[0][t] + redA[1][t] + redA[2][t] + redA[3][t] + self;
    out[(size_t)i * 256 + 128 + t] = 0.01f * (dinv2[i] * s + b2[t]);
  }
}

// ---------------- launch ----------------

extern "C" void kernel_launch(void* const* d_in, const int* in_sizes, int n_in,
                              void* d_out, int out_size, void* d_ws, size_t ws_size,
                              hipStream_t stream) {
  const float* x  = (const float*)d_in[0];
  const int*   ei = (const int*)d_in[1];     // int32 per harness dtype rules
  const float* W1 = (const float*)d_in[2];
  const float* b1 = (const float*)d_in[3];
  const float* W2 = (const float*)d_in[4];
  const float* b2 = (const float*)d_in[5];
  float* out = (float*)d_out;
  char* ws = (char*)d_ws;

  float* g1              = (float*)(ws + OFF_G1);
  unsigned short* g2b    = (unsigned short*)(ws + OFF_G2B);
  u64* AT                = (u64*)(ws + OFF_AT);
  u64* A2T               = (u64*)(ws + OFF_A2T);
  unsigned* cnt          = (unsigned*)(ws + OFF_CNT);
  unsigned* fill         = (unsigned*)(ws + OFF_FILL);
  unsigned* row_ptr      = (unsigned*)(ws + OFF_RP);
  unsigned* csr_src      = (unsigned*)(ws + OFF_CSR);
  float* dinv1           = (float*)(ws + OFF_DI1);
  float* dinv2           = (float*)(ws + OFF_DI2);

  k_zero<<<1024, 256, 0, stream>>>(AT, cnt, fill);
  k_hist<<<NE / 256, 256, 0, stream>>>(ei, cnt);
  k_scan<<<1, 1024, 0, stream>>>(cnt, row_ptr, dinv1);
  k_scatter<<<NE / 256, 256, 0, stream>>>(ei, row_ptr, fill, csr_src, AT);
  k_a2t<<<NN, 512, 0, stream>>>(AT, A2T, dinv2);
  dim3 gg(NN / 64, 4);
  k_gemm<<<gg, 256, 0, stream>>>(x, W1, W2, dinv1, dinv2, g1, g2b);
  k_spmm1<<<NN, 256, 0, stream>>>(g1, row_ptr, csr_src, dinv1, b1, out);
  k_spmm2<<<NN, 256, 0, stream>>>(g2b, A2T, dinv2, b2, out);
}